// Round 12
// baseline (71.283 us; speedup 1.0000x reference)
//
#include <hip/hip_runtime.h>

#define B_SZ 8192
#define C_DIM 128
#define D_DIM 512
#define PAIR_CAP 65536
#define NBINS 256
#define BIN_STRIDE 16   // floats; 64 B -> one cache line per bin
#define NT 8            // A-panels per gemm block

typedef __bf16 bf16x8 __attribute__((ext_vector_type(8)));
typedef float  f32x4  __attribute__((ext_vector_type(4)));

// RNE float -> bf16 (inputs are finite positive probabilities; no NaN path)
__device__ inline unsigned int f2bf(float f) {
    unsigned int u = __builtin_bit_cast(unsigned int, f);
    u += 0x7FFFu + ((u >> 16) & 1u);
    return u >> 16;
}

// ---------------------------------------------------------------------------
// Kernel 0 (fused prep): blocks [0,1024) convert P,Q fp32->bf16 into ws;
// blocks [1024,3072) compute ordered top-5 keys of feat rows (one wave/row,
// 5 rounds of wave-argmax, lower-index tiebreak).
// Block 0: threads zero the 256 accumulator bins; thread 0 zeroes cnt.
// ---------------------------------------------------------------------------
__global__ __launch_bounds__(256) void prep_kernel(
    const float* __restrict__ feat,
    const float* __restrict__ P, const float* __restrict__ Q,
    unsigned short* __restrict__ bfP, unsigned short* __restrict__ bfQ,
    unsigned long long* __restrict__ keys,
    float* __restrict__ accbins, int* __restrict__ cnt)
{
    if (blockIdx.x == 0) {
        accbins[threadIdx.x * BIN_STRIDE] = 0.0f;
        if (threadIdx.x == 0) *cnt = 0;
    }

    if (blockIdx.x < 1024) {
        const int half = (B_SZ * C_DIM) / 8;          // 131072 vec8 per array
        int idx = blockIdx.x * 256 + threadIdx.x;
        const float* src = P; unsigned short* dst = bfP;
        if (idx >= half) { idx -= half; src = Q; dst = bfQ; }
        float4 a = *reinterpret_cast<const float4*>(src + (size_t)idx * 8);
        float4 b = *reinterpret_cast<const float4*>(src + (size_t)idx * 8 + 4);
        uint4 w;
        w.x = f2bf(a.x) | (f2bf(a.y) << 16);
        w.y = f2bf(a.z) | (f2bf(a.w) << 16);
        w.z = f2bf(b.x) | (f2bf(b.y) << 16);
        w.w = f2bf(b.z) | (f2bf(b.w) << 16);
        *reinterpret_cast<uint4*>(dst + (size_t)idx * 8) = w;
        return;
    }

    const int lane = threadIdx.x & 63;
    const int wv   = threadIdx.x >> 6;
    const int row  = (blockIdx.x - 1024) * 4 + wv;
    const float* f = feat + (size_t)row * D_DIM;

    const int base = lane * 8;
    float v[8];
    float4 a = *reinterpret_cast<const float4*>(f + base);
    float4 b = *reinterpret_cast<const float4*>(f + base + 4);
    v[0]=a.x; v[1]=a.y; v[2]=a.z; v[3]=a.w;
    v[4]=b.x; v[5]=b.y; v[6]=b.z; v[7]=b.w;

    unsigned sel = 0;
    unsigned long long key = 0;
    for (int k = 0; k < 5; ++k) {
        float best = -3.0e38f;
        int  bidx = 0x7fffffff;
        #pragma unroll
        for (int j = 0; j < 8; ++j) {
            if (!((sel >> j) & 1u)) {
                float val = v[j];
                int   idx = base + j;
                if (val > best || (val == best && idx < bidx)) { best = val; bidx = idx; }
            }
        }
        #pragma unroll
        for (int off = 32; off > 0; off >>= 1) {
            float ov = __shfl_xor(best, off);
            int   oi = __shfl_xor(bidx, off);
            if (ov > best || (ov == best && oi < bidx)) { best = ov; bidx = oi; }
        }
        key |= (unsigned long long)(unsigned)bidx << (10 * k);
        if (bidx >= base && bidx < base + 8) sel |= 1u << (bidx - base);
    }
    if (lane == 0) keys[row] = key;
}

// ---------------------------------------------------------------------------
// Kernel 1 (fused): blocks [0,512): GEMM + BCE-log-product.
//   Block b: B-tile bj=b&63 staged ONCE into 32 KB LDS (swizzled gload_lds),
//   then hoisted into registers bfr[4][4] (64 VGPR, loop-invariant) -> the
//   8-panel main loop has ZERO LDS traffic and ZERO barriers. A panels
//   (bi = (b>>6)*8+t) stream DIRECTLY global->VGPR (plain L2 reads at full
//   rate -- R9/R11 evidence: the gload_lds DMA path sustains only ~50 GB/s/CU
//   and was the real bottleneck). 2x2 waves, 64x64 out each; 2 blocks/CU.
// blocks [512,1536): pair_find for OFF-DIAGONAL key duplicates (expected 0).
// ---------------------------------------------------------------------------
__global__ __launch_bounds__(256) void gemm_pf_kernel(
    const unsigned short* __restrict__ bfP,
    const unsigned short* __restrict__ bfQ,
    const unsigned long long* __restrict__ keys,
    unsigned int* __restrict__ pairs, int* __restrict__ cnt,
    float* __restrict__ accbins)
{
    __shared__ unsigned short Bs[128 * 128];   // 32 KB
    __shared__ float wsum[4];

    const int tid = threadIdx.x;

    if (blockIdx.x >= 512) {
        // ---- pair-find tail blocks ----
        unsigned long long* kjs = reinterpret_cast<unsigned long long*>(Bs);
        const int b2 = blockIdx.x - 512;
        const int ibase = (b2 >> 5) * 256;
        const int jbase = (b2 & 31) * 256;
        kjs[tid] = keys[jbase + tid];
        __syncthreads();
        const int i = ibase + tid;
        const unsigned long long ki = keys[i];
        #pragma unroll
        for (int batch = 0; batch < 16; ++batch) {
            unsigned long long kk[16];
            #pragma unroll
            for (int x = 0; x < 8; ++x) {
                ulonglong2 two = *reinterpret_cast<const ulonglong2*>(&kjs[batch * 16 + x * 2]);
                kk[x * 2] = two.x; kk[x * 2 + 1] = two.y;
            }
            #pragma unroll
            for (int x = 0; x < 16; ++x) {
                const int j = jbase + batch * 16 + x;
                if (kk[x] == ki && j != i) {
                    int slot = atomicAdd(cnt, 1);
                    if (slot < PAIR_CAP)
                        pairs[slot] = ((unsigned)i << 13) | (unsigned)j;
                }
            }
        }
        return;
    }

    const int b   = blockIdx.x;
    const int bj  = b & 63;
    const int pg  = b >> 6;
    const int col0 = bj << 7;

    const int l  = tid & 63;
    const int wv = tid >> 6;
    const int wm = wv >> 1, wn = wv & 1;     // 2x2 waves
    const int g8 = l >> 4, q = l & 15;

    // ---- stage B tile once: 8 gload_lds / thread, pre-swizzled source ----
    #pragma unroll
    for (int it = 0; it < 8; ++it) {
        const int g  = it * 256 + tid;       // granule (16B), [0,2048)
        const int rr = g >> 4;
        const int s  = g & 15;
        const int cw = s ^ (rr & 7);         // pre-swizzled source chunk
        const unsigned short* sB = bfQ + (size_t)(col0 + rr) * C_DIM + cw * 8;
        __builtin_amdgcn_global_load_lds(
            (const __attribute__((address_space(1))) void*)sB,
            (__attribute__((address_space(3))) void*)(&Bs[g * 8]), 16, 0, 0);
    }
    __syncthreads();

    // ---- hoist B fragments to registers (loop-invariant): 16 ds_read_b128 ----
    bf16x8 bfr[4][4];                         // [ks][ni]
    #pragma unroll
    for (int ks = 0; ks < 4; ++ks)
        #pragma unroll
        for (int ni = 0; ni < 4; ++ni) {
            const int rr = wn * 64 + ni * 16 + q;
            bfr[ks][ni] = *reinterpret_cast<const bf16x8*>(
                &Bs[rr * 128 + ((ks * 32 + g8 * 8) ^ ((rr & 7) << 3))]);
        }

    // ---- main loop: 8 A-panels, A direct global->reg, no barriers ----
    float lsum = 0.0f;
    for (int t = 0; t < NT; ++t) {
        const int bi  = pg * NT + t;
        const int row0 = bi << 7;

        bf16x8 af[4][4];                      // [mi][ks]
        #pragma unroll
        for (int mi = 0; mi < 4; ++mi)
            #pragma unroll
            for (int ks = 0; ks < 4; ++ks)
                af[mi][ks] = *reinterpret_cast<const bf16x8*>(
                    bfP + (size_t)(row0 + wm * 64 + mi * 16 + q) * C_DIM + ks * 32 + g8 * 8);

        f32x4 accf[4][4];
        #pragma unroll
        for (int mi = 0; mi < 4; ++mi)
            #pragma unroll
            for (int ni = 0; ni < 4; ++ni) accf[mi][ni] = (f32x4){0.f, 0.f, 0.f, 0.f};

        #pragma unroll
        for (int ks = 0; ks < 4; ++ks)
            #pragma unroll
            for (int mi = 0; mi < 4; ++mi)
                #pragma unroll
                for (int ni = 0; ni < 4; ++ni)
                    accf[mi][ni] = __builtin_amdgcn_mfma_f32_16x16x32_bf16(
                        af[mi][ks], bfr[ks][ni], accf[mi][ni], 0, 0, 0);

        // ---- epilogue: product of 64 factors, one log2, accumulate ----
        float pr[4] = {1.0f, 1.0f, 1.0f, 1.0f};
        if (bi == bj) {
            #pragma unroll
            for (int mi = 0; mi < 4; ++mi) {
                #pragma unroll
                for (int ni = 0; ni < 4; ++ni) {
                    const int lj = wn * 64 + ni * 16 + q;
                    #pragma unroll
                    for (int r = 0; r < 4; ++r) {
                        const float p = accf[mi][ni][r];
                        const int li = wm * 64 + mi * 16 + g8 * 4 + r;
                        pr[r] *= (li == lj) ? p : (1.0f - p);
                    }
                }
            }
        } else {
            #pragma unroll
            for (int mi = 0; mi < 4; ++mi)
                #pragma unroll
                for (int ni = 0; ni < 4; ++ni)
                    #pragma unroll
                    for (int r = 0; r < 4; ++r)
                        pr[r] *= 1.0f - accf[mi][ni][r];
        }
        lsum += __log2f((pr[0] * pr[1]) * (pr[2] * pr[3]));
    }

    // ---- block reduction, one atomic into a padded bin ----
    #pragma unroll
    for (int off = 32; off > 0; off >>= 1) lsum += __shfl_xor(lsum, off);
    if (l == 0) wsum[wv] = lsum;
    __syncthreads();
    if (tid == 0) {
        float s = wsum[0] + wsum[1] + wsum[2] + wsum[3];
        atomicAdd(accbins + (b & (NBINS - 1)) * BIN_STRIDE,
                  s * 0.69314718055994531f);
    }
}

// ---------------------------------------------------------------------------
// Kernel 2 (fused): duplicate-pair correction (expected 0 pairs) + bin sum +
// finalize. Single block of 256 threads.
// ---------------------------------------------------------------------------
__global__ __launch_bounds__(256) void fix_final_kernel(
    const unsigned int* __restrict__ pairs, const int* __restrict__ cnt,
    const float* __restrict__ P, const float* __restrict__ Q,
    const float* __restrict__ accbins, float* __restrict__ out)
{
    __shared__ float wsum[4];
    __shared__ float bsum[4];
    const int lane = threadIdx.x & 63;
    const int w    = threadIdx.x >> 6;
    const int count = min(*cnt, PAIR_CAP);

    float lsum = 0.0f;
    for (int p = w; p < count; p += 4) {
        const unsigned code = pairs[p];
        const int i = code >> 13;
        const int j = code & 8191;
        float2 a = *reinterpret_cast<const float2*>(P + (size_t)i * C_DIM + lane * 2);
        float2 b = *reinterpret_cast<const float2*>(Q + (size_t)j * C_DIM + lane * 2);
        float s = fmaf(a.x, b.x, a.y * b.y);
        #pragma unroll
        for (int off = 32; off > 0; off >>= 1) s += __shfl_xor(s, off);
        if (lane == 0)
            lsum += fmaxf(__logf(s), -100.0f) - __logf(1.0f - s);
    }
    if (lane == 0) wsum[w] = lsum;

    float bv = accbins[threadIdx.x * BIN_STRIDE];
    #pragma unroll
    for (int off = 32; off > 0; off >>= 1) bv += __shfl_xor(bv, off);
    if (lane == 0) bsum[w] = bv;
    __syncthreads();

    if (threadIdx.x == 0) {
        float total = wsum[0] + wsum[1] + wsum[2] + wsum[3]
                    + bsum[0] + bsum[1] + bsum[2] + bsum[3];
        out[0] = -total / (float)((long long)B_SZ * (long long)B_SZ);
    }
}

extern "C" void kernel_launch(void* const* d_in, const int* in_sizes, int n_in,
                              void* d_out, int out_size, void* d_ws, size_t ws_size,
                              hipStream_t stream)
{
    const float* feat = (const float*)d_in[0];   // unlabel_feat     (8192, 512)
    const float* prob = (const float*)d_in[1];   // unlabel_prob     (8192, 128)
    const float* rot  = (const float*)d_in[2];   // rot_unlabel_prob (8192, 128)
    float* out = (float*)d_out;

    char* ws = (char*)d_ws;
    unsigned long long* keys = (unsigned long long*)ws;               // 64 KB
    int*   cnt     = (int*)(ws + 65536);
    float* accbins = (float*)(ws + 66560);                            // 16 KB
    unsigned short* bfP = (unsigned short*)(ws + 66560 + 16384);      // 2 MB
    unsigned short* bfQ = bfP + (size_t)B_SZ * C_DIM;                 // 2 MB
    unsigned int* pairs = (unsigned int*)(ws + 66560 + 16384 + 4 * 1024 * 1024);

    prep_kernel<<<3072, 256, 0, stream>>>(feat, prob, rot, bfP, bfQ, keys, accbins, cnt);
    gemm_pf_kernel<<<512 + 1024, 256, 0, stream>>>(bfP, bfQ, keys, pairs, cnt, accbins);
    fix_final_kernel<<<1, 256, 0, stream>>>(pairs, cnt, prob, rot, accbins, out);
}

// Round 13
// 57.085 us; speedup vs baseline: 1.2487x; 1.2487x over previous
//
#include <hip/hip_runtime.h>

#define B_SZ 8192
#define C_DIM 128
#define D_DIM 512
#define PAIR_CAP 65536
#define NBINS 256
#define BIN_STRIDE 16   // floats; 64 B -> one cache line per bin

typedef __bf16 bf16x8 __attribute__((ext_vector_type(8)));
typedef float  f32x4  __attribute__((ext_vector_type(4)));

// RNE float -> bf16 (inputs are finite positive probabilities; no NaN path)
__device__ inline unsigned int f2bf(float f) {
    unsigned int u = __builtin_bit_cast(unsigned int, f);
    u += 0x7FFFu + ((u >> 16) & 1u);
    return u >> 16;
}

// ---------------------------------------------------------------------------
// Kernel 0 (fused prep): blocks [0,1024) convert P,Q fp32->bf16 into ws;
// blocks [1024,3072) compute ordered top-5 keys of feat rows (one wave/row,
// 5 rounds of wave-argmax, lower-index tiebreak).
// Block 0: threads zero the 256 accumulator bins; thread 0 zeroes cnt.
// ---------------------------------------------------------------------------
__global__ __launch_bounds__(256) void prep_kernel(
    const float* __restrict__ feat,
    const float* __restrict__ P, const float* __restrict__ Q,
    unsigned short* __restrict__ bfP, unsigned short* __restrict__ bfQ,
    unsigned long long* __restrict__ keys,
    float* __restrict__ accbins, int* __restrict__ cnt)
{
    if (blockIdx.x == 0) {
        accbins[threadIdx.x * BIN_STRIDE] = 0.0f;
        if (threadIdx.x == 0) *cnt = 0;
    }

    if (blockIdx.x < 1024) {
        const int half = (B_SZ * C_DIM) / 8;          // 131072 vec8 per array
        int idx = blockIdx.x * 256 + threadIdx.x;
        const float* src = P; unsigned short* dst = bfP;
        if (idx >= half) { idx -= half; src = Q; dst = bfQ; }
        float4 a = *reinterpret_cast<const float4*>(src + (size_t)idx * 8);
        float4 b = *reinterpret_cast<const float4*>(src + (size_t)idx * 8 + 4);
        uint4 w;
        w.x = f2bf(a.x) | (f2bf(a.y) << 16);
        w.y = f2bf(a.z) | (f2bf(a.w) << 16);
        w.z = f2bf(b.x) | (f2bf(b.y) << 16);
        w.w = f2bf(b.z) | (f2bf(b.w) << 16);
        *reinterpret_cast<uint4*>(dst + (size_t)idx * 8) = w;
        return;
    }

    const int lane = threadIdx.x & 63;
    const int wv   = threadIdx.x >> 6;
    const int row  = (blockIdx.x - 1024) * 4 + wv;
    const float* f = feat + (size_t)row * D_DIM;

    const int base = lane * 8;
    float v[8];
    float4 a = *reinterpret_cast<const float4*>(f + base);
    float4 b = *reinterpret_cast<const float4*>(f + base + 4);
    v[0]=a.x; v[1]=a.y; v[2]=a.z; v[3]=a.w;
    v[4]=b.x; v[5]=b.y; v[6]=b.z; v[7]=b.w;

    unsigned sel = 0;
    unsigned long long key = 0;
    for (int k = 0; k < 5; ++k) {
        float best = -3.0e38f;
        int  bidx = 0x7fffffff;
        #pragma unroll
        for (int j = 0; j < 8; ++j) {
            if (!((sel >> j) & 1u)) {
                float val = v[j];
                int   idx = base + j;
                if (val > best || (val == best && idx < bidx)) { best = val; bidx = idx; }
            }
        }
        #pragma unroll
        for (int off = 32; off > 0; off >>= 1) {
            float ov = __shfl_xor(best, off);
            int   oi = __shfl_xor(bidx, off);
            if (ov > best || (ov == best && oi < bidx)) { best = ov; bidx = oi; }
        }
        key |= (unsigned long long)(unsigned)bidx << (10 * k);
        if (bidx >= base && bidx < base + 8) sel |= 1u << (bidx - base);
    }
    if (lane == 0) keys[row] = key;
}

// ---------------------------------------------------------------------------
// Kernel 1: pair-find, OFF-DIAGONAL key duplicates only (expected ~0).
// ---------------------------------------------------------------------------
__global__ __launch_bounds__(256) void pair_find_kernel(
    const unsigned long long* __restrict__ keys,
    unsigned int* __restrict__ pairs, int* __restrict__ cnt)
{
    __shared__ unsigned long long kjs[256];
    const int ibase = (blockIdx.x >> 5) * 256;
    const int jbase = (blockIdx.x & 31) * 256;
    kjs[threadIdx.x] = keys[jbase + threadIdx.x];
    __syncthreads();

    const int i = ibase + threadIdx.x;
    const unsigned long long ki = keys[i];

    #pragma unroll
    for (int batch = 0; batch < 16; ++batch) {
        unsigned long long kk[16];
        #pragma unroll
        for (int x = 0; x < 8; ++x) {
            ulonglong2 two = *reinterpret_cast<const ulonglong2*>(&kjs[batch * 16 + x * 2]);
            kk[x * 2] = two.x; kk[x * 2 + 1] = two.y;
        }
        #pragma unroll
        for (int x = 0; x < 16; ++x) {
            const int j = jbase + batch * 16 + x;
            if (kk[x] == ki && j != i) {
                int slot = atomicAdd(cnt, 1);
                if (slot < PAIR_CAP)
                    pairs[slot] = ((unsigned)i << 13) | (unsigned)j;
            }
        }
    }
}

// ---------------------------------------------------------------------------
// Kernel 2: m97-structure GEMM + BCE-log-product.
// 4096 blocks (128x128 tile, 4 waves 2x2, 64x64 out each). K=128 sliced into
// 4 x BK=32; A,B slices double-buffered in 4x8KB LDS (32 KB total) ->
// 3-4 blocks/CU co-resident: slice stage of one block overlaps compute of
// others (m114 overlap needs >=3 blocks/CU -- R9-R12 ran 1-2 and stalled).
// LDS layout per slice: 128 rows x 64B; 16B-granule ROTATION G = r*4+((c+r)&3)
// -> bank-quad (5r+c) mod 8 covers all 8 quads per 8 rows => 2-way (free).
// Applied as pre-swizzled gload_lds SOURCE + same mapping on ds_read (both
// sides, LDS dest stays linear).
// ---------------------------------------------------------------------------
__global__ __launch_bounds__(256, 3) void gemm_kernel(
    const unsigned short* __restrict__ bfP,
    const unsigned short* __restrict__ bfQ,
    float* __restrict__ accbins)
{
    __shared__ unsigned short As[2][128 * 32];   // 2 x 8 KB
    __shared__ unsigned short Bs[2][128 * 32];   // 2 x 8 KB
    __shared__ float wsum[4];

    const int tid = threadIdx.x;
    const int bi  = blockIdx.x & 63;
    const int bj  = blockIdx.x >> 6;
    const int row0 = bi << 7, col0 = bj << 7;

    const int l  = tid & 63;
    const int wv = tid >> 6;
    const int wm = wv >> 1, wn = wv & 1;     // 2x2 waves
    const int g8 = l >> 4, q = l & 15;

    // stage one BK=32 slice of A and B into buffer buf: 2 granules/thread each
    auto STAGE = [&](int buf, int kk) {
        #pragma unroll
        for (int it = 0; it < 2; ++it) {
            const int G  = it * 256 + tid;        // granule (16B) in [0,512)
            const int r  = G >> 2;
            const int c  = (G - r) & 3;           // logical col chunk (inverse rot)
            const unsigned short* sA = bfP + (size_t)(row0 + r) * C_DIM + kk * 32 + c * 8;
            const unsigned short* sB = bfQ + (size_t)(col0 + r) * C_DIM + kk * 32 + c * 8;
            __builtin_amdgcn_global_load_lds(
                (const __attribute__((address_space(1))) void*)sA,
                (__attribute__((address_space(3))) void*)(&As[buf][G * 8]), 16, 0, 0);
            __builtin_amdgcn_global_load_lds(
                (const __attribute__((address_space(1))) void*)sB,
                (__attribute__((address_space(3))) void*)(&Bs[buf][G * 8]), 16, 0, 0);
        }
    };

    STAGE(0, 0);

    f32x4 accf[4][4];
    #pragma unroll
    for (int mi = 0; mi < 4; ++mi)
        #pragma unroll
        for (int ni = 0; ni < 4; ++ni) accf[mi][ni] = (f32x4){0.f, 0.f, 0.f, 0.f};

    __syncthreads();

    int cur = 0;
    #pragma unroll
    for (int kk = 0; kk < 4; ++kk) {
        if (kk < 3) STAGE(cur ^ 1, kk + 1);

        bf16x8 af[4], bfr[4];
        #pragma unroll
        for (int mi = 0; mi < 4; ++mi) {
            const int rr = wm * 64 + mi * 16 + q;
            af[mi] = *reinterpret_cast<const bf16x8*>(
                &As[cur][(rr * 4 + ((g8 + rr) & 3)) * 8]);
        }
        #pragma unroll
        for (int ni = 0; ni < 4; ++ni) {
            const int rr = wn * 64 + ni * 16 + q;
            bfr[ni] = *reinterpret_cast<const bf16x8*>(
                &Bs[cur][(rr * 4 + ((g8 + rr) & 3)) * 8]);
        }
        #pragma unroll
        for (int mi = 0; mi < 4; ++mi)
            #pragma unroll
            for (int ni = 0; ni < 4; ++ni)
                accf[mi][ni] = __builtin_amdgcn_mfma_f32_16x16x32_bf16(
                    af[mi], bfr[ni], accf[mi][ni], 0, 0, 0);

        __syncthreads();                      // next slice staged; buffer safe
        cur ^= 1;
    }

    // ---- epilogue: product of 64 factors, one log2 per thread ----
    float pr[4] = {1.0f, 1.0f, 1.0f, 1.0f};
    if (bi == bj) {
        #pragma unroll
        for (int mi = 0; mi < 4; ++mi) {
            #pragma unroll
            for (int ni = 0; ni < 4; ++ni) {
                const int lj = wn * 64 + ni * 16 + q;
                #pragma unroll
                for (int r = 0; r < 4; ++r) {
                    const float p = accf[mi][ni][r];
                    const int li = wm * 64 + mi * 16 + g8 * 4 + r;
                    pr[r] *= (li == lj) ? p : (1.0f - p);
                }
            }
        }
    } else {
        #pragma unroll
        for (int mi = 0; mi < 4; ++mi)
            #pragma unroll
            for (int ni = 0; ni < 4; ++ni)
                #pragma unroll
                for (int r = 0; r < 4; ++r)
                    pr[r] *= 1.0f - accf[mi][ni][r];
    }
    float lsum = __log2f((pr[0] * pr[1]) * (pr[2] * pr[3]));

    #pragma unroll
    for (int off = 32; off > 0; off >>= 1) lsum += __shfl_xor(lsum, off);
    if (l == 0) wsum[wv] = lsum;
    __syncthreads();
    if (tid == 0) {
        float s = wsum[0] + wsum[1] + wsum[2] + wsum[3];
        atomicAdd(accbins + (blockIdx.x & (NBINS - 1)) * BIN_STRIDE,
                  s * 0.69314718055994531f);
    }
}

// ---------------------------------------------------------------------------
// Kernel 3 (fused): duplicate-pair correction (expected 0 pairs) + bin sum +
// finalize. Single block of 256 threads.
// ---------------------------------------------------------------------------
__global__ __launch_bounds__(256) void fix_final_kernel(
    const unsigned int* __restrict__ pairs, const int* __restrict__ cnt,
    const float* __restrict__ P, const float* __restrict__ Q,
    const float* __restrict__ accbins, float* __restrict__ out)
{
    __shared__ float wsum[4];
    __shared__ float bsum[4];
    const int lane = threadIdx.x & 63;
    const int w    = threadIdx.x >> 6;
    const int count = min(*cnt, PAIR_CAP);

    float lsum = 0.0f;
    for (int p = w; p < count; p += 4) {
        const unsigned code = pairs[p];
        const int i = code >> 13;
        const int j = code & 8191;
        float2 a = *reinterpret_cast<const float2*>(P + (size_t)i * C_DIM + lane * 2);
        float2 b = *reinterpret_cast<const float2*>(Q + (size_t)j * C_DIM + lane * 2);
        float s = fmaf(a.x, b.x, a.y * b.y);
        #pragma unroll
        for (int off = 32; off > 0; off >>= 1) s += __shfl_xor(s, off);
        if (lane == 0)
            lsum += fmaxf(__logf(s), -100.0f) - __logf(1.0f - s);
    }
    if (lane == 0) wsum[w] = lsum;

    float bv = accbins[threadIdx.x * BIN_STRIDE];
    #pragma unroll
    for (int off = 32; off > 0; off >>= 1) bv += __shfl_xor(bv, off);
    if (lane == 0) bsum[w] = bv;
    __syncthreads();

    if (threadIdx.x == 0) {
        float total = wsum[0] + wsum[1] + wsum[2] + wsum[3]
                    + bsum[0] + bsum[1] + bsum[2] + bsum[3];
        out[0] = -total / (float)((long long)B_SZ * (long long)B_SZ);
    }
}

extern "C" void kernel_launch(void* const* d_in, const int* in_sizes, int n_in,
                              void* d_out, int out_size, void* d_ws, size_t ws_size,
                              hipStream_t stream)
{
    const float* feat = (const float*)d_in[0];   // unlabel_feat     (8192, 512)
    const float* prob = (const float*)d_in[1];   // unlabel_prob     (8192, 128)
    const float* rot  = (const float*)d_in[2];   // rot_unlabel_prob (8192, 128)
    float* out = (float*)d_out;

    char* ws = (char*)d_ws;
    unsigned long long* keys = (unsigned long long*)ws;               // 64 KB
    int*   cnt     = (int*)(ws + 65536);
    float* accbins = (float*)(ws + 66560);                            // 16 KB
    unsigned short* bfP = (unsigned short*)(ws + 66560 + 16384);      // 2 MB
    unsigned short* bfQ = bfP + (size_t)B_SZ * C_DIM;                 // 2 MB
    unsigned int* pairs = (unsigned int*)(ws + 66560 + 16384 + 4 * 1024 * 1024);

    prep_kernel<<<3072, 256, 0, stream>>>(feat, prob, rot, bfP, bfQ, keys, accbins, cnt);
    pair_find_kernel<<<1024, 256, 0, stream>>>(keys, pairs, cnt);
    gemm_kernel<<<4096, 256, 0, stream>>>(bfP, bfQ, accbins);
    fix_final_kernel<<<1, 256, 0, stream>>>(pairs, cnt, prob, rot, accbins, out);
}